// Round 8
// baseline (24.472 us; speedup 1.0000x reference)
//
#include <hip/hip_runtime.h>

// x: (N=64, C=3, W=16, T=128, V=25, M=2) fp32, row-major
// strides (elems): N:307200, C:102400, W:6400, T:50, V:2, M:1
// b = ((n*T+t)*V+v)*M+m ; local = t*50+v*2+m == b % 6400 (bijective, order-preserving)
// xr[c][w] = flat elem i = c*16+w of permuted (W,C) block -> (c_orig,w_orig)=(i%3,i/3)
//
// R8: input staged via __builtin_amdgcn_global_load_lds (width=16): 48 x 1KB async
// loads per block with NO register destination -> guaranteed 48KB in flight/block,
// immune to compiler load-windowing (the suspected residual limiter in R5-R7).
// Block = 128 threads handles 256 consecutive b (same n; 6400%256==0).
// LDS slice layout: lds[i*256 + j] = xr slice i (=c*16+w), j = b - b0.
// Compute: thread t owns b0+2t, b0+2t+1 -> float2 ds_reads.
// Epilogue: reuse LDS (barrier-protected) for XOR-swizzled output staging,
// then lane-contiguous float4 stores (proven -4us in R4).
// out: (B,4,4) fp32, B = 409600. Grid exact: 1600 blocks x 128 threads.

__global__ void __launch_bounds__(128)
gaussian_embed_kernel(const float* __restrict__ x, float* __restrict__ out) {
    __shared__ float lds[48 * 256];  // 48KB: input slices, later reused for output staging

    const int t    = threadIdx.x;
    const int lane = t & 63;
    const int wv   = t >> 6;          // wave 0 or 1
    const int b0   = blockIdx.x * 256;
    const int n    = b0 / 6400;
    const int rem  = b0 - n * 6400;   // multiple of 256
    const float* __restrict__ xn = x + (size_t)n * 307200 + rem;

    // ---- Phase 1: async-stage 48 slices, 24 per wave (1KB each, lane*16B dest)
#pragma unroll
    for (int k = 0; k < 24; ++k) {
        const int i = wv * 24 + k;               // slice = c*16 + w
        const float* src = xn + (i % 3) * 102400 + (i / 3) * 6400 + lane * 4;
        __builtin_amdgcn_global_load_lds(
            (const __attribute__((address_space(1))) void*)src,
            (__attribute__((address_space(3))) void*)&lds[i * 256],
            16, 0, 0);
    }
    asm volatile("s_waitcnt vmcnt(0)" ::: "memory");
    __syncthreads();

    // ---- Phase 2: single-pass moments from LDS (thread t owns local b = 2t, 2t+1)
    float s0[2] = {0,0}, s1[2] = {0,0}, s2[2] = {0,0};
    float p00[2] = {0,0}, p01[2] = {0,0}, p02[2] = {0,0};
    float p11[2] = {0,0}, p12[2] = {0,0}, p22[2] = {0,0};
#pragma unroll
    for (int w = 0; w < 16; ++w) {
        const float2 av = *(const float2*)&lds[(w)      * 256 + 2 * t];
        const float2 bv = *(const float2*)&lds[(w + 16) * 256 + 2 * t];
        const float2 cv = *(const float2*)&lds[(w + 32) * 256 + 2 * t];
        const float a[2]  = {av.x, av.y};
        const float bb[2] = {bv.x, bv.y};
        const float cc[2] = {cv.x, cv.y};
#pragma unroll
        for (int j = 0; j < 2; ++j) {
            s0[j]  += a[j];          s1[j]  += bb[j];          s2[j]  += cc[j];
            p00[j] += a[j] * a[j];   p01[j] += a[j] * bb[j];   p02[j] += a[j] * cc[j];
            p11[j] += bb[j] * bb[j]; p12[j] += bb[j] * cc[j];  p22[j] += cc[j] * cc[j];
        }
    }

    // ---- Phase 3: epilogue per b -> registers
    float4 rows[2][4];
#pragma unroll
    for (int j = 0; j < 2; ++j) {
        const float m0 = s0[j] * 0.0625f, m1 = s1[j] * 0.0625f, m2 = s2[j] * 0.0625f;
        const float inv15 = 1.f / 15.f;
        const float c00 = (p00[j] - 16.f * m0 * m0) * inv15;
        const float c01 = (p01[j] - 16.f * m0 * m1) * inv15;
        const float c02 = (p02[j] - 16.f * m0 * m2) * inv15;
        const float c11 = (p11[j] - 16.f * m1 * m1) * inv15;
        const float c12 = (p12[j] - 16.f * m1 * m2) * inv15;
        const float c22 = (p22[j] - 16.f * m2 * m2) * inv15;

        const float tr    = c00 + c11 + c22;
        const float invtr = 1.f / tr;
        const float diag  = 0.001f * tr;
        const float a  = c00 * invtr + diag;
        const float bq = c01 * invtr;
        const float cq = c02 * invtr;
        const float d  = c11 * invtr + diag;
        const float e  = c12 * invtr;
        const float g  = c22 * invtr + diag;

        const float det = a * (d * g - e * e) - bq * (bq * g - cq * e) + cq * (bq * e - cq * d);
        const float dsp = rsqrtf(sqrtf(det));  // det^(-1/4)

        const float om01 = dsp * (bq + m0 * m1);
        const float om02 = dsp * (cq + m0 * m2);
        const float om12 = dsp * (e + m1 * m2);
        const float dm0 = dsp * m0, dm1 = dsp * m1, dm2 = dsp * m2;

        rows[j][0] = make_float4(dsp * (a + m0 * m0), om01, om02, dm0);
        rows[j][1] = make_float4(om01, dsp * (d + m1 * m1), om12, dm1);
        rows[j][2] = make_float4(om02, om12, dsp * (g + m2 * m2), dm2);
        rows[j][3] = make_float4(dm0, dm1, dm2, dsp);
    }

    __syncthreads();  // all ds_reads of input done before LDS reuse

    // ---- Phase 4: stage output in LDS (XOR-swizzled), 8 float4 per thread
    float4* lo = (float4*)lds;
    {
        const int base = t * 8;
        const int sw   = t & 7;
#pragma unroll
        for (int j = 0; j < 2; ++j) {
#pragma unroll
            for (int r = 0; r < 4; ++r)
                lo[base + ((j * 4 + r) ^ sw)] = rows[j][r];
        }
    }
    __syncthreads();

    // ---- Phase 5: coalesced block store (1024 float4 = 16KB contiguous)
    float4* __restrict__ o = (float4*)out + (size_t)blockIdx.x * 1024;
#pragma unroll
    for (int k2 = 0; k2 < 8; ++k2) {
        const int g  = k2 * 128 + t;
        const int ts = g >> 3;
        const int it = g & 7;
        o[g] = lo[ts * 8 + (it ^ (ts & 7))];
    }
}

extern "C" void kernel_launch(void* const* d_in, const int* in_sizes, int n_in,
                              void* d_out, int out_size, void* d_ws, size_t ws_size,
                              hipStream_t stream) {
    const float* x = (const float*)d_in[0];
    float* out = (float*)d_out;
    const int B = in_sizes[0] / 48;   // 409600
    const int threads = 128;
    const int blocks = B / 256;       // 1600 exact (no tail; syncthreads-safe)
    gaussian_embed_kernel<<<blocks, threads, 0, stream>>>(x, out);
}